// Round 1
// baseline (550.334 us; speedup 1.0000x reference)
//
#include <hip/hip_runtime.h>
#include <stdint.h>

#define NN 8000            // nodes
#define UU 64              // units
#define EE 64000           // edges per support
#define BB 32              // batch
#define NB 256000          // NN*BB rows of the logical GEMM
#define KP 352             // padded K (5*64 state + 5*2 input + pad)
#define HXS 512000         // NN*UU (per-batch stride in hx)

typedef __attribute__((ext_vector_type(8))) __bf16 bf16x8;
typedef __attribute__((ext_vector_type(4))) float f32x4;
static_assert(sizeof(bf16x8) == 16, "bf16x8 must be 16B");

__device__ __forceinline__ unsigned short f2bf(float f){
  unsigned int u = __builtin_bit_cast(unsigned int, f);
  u += 0x7fffu + ((u >> 16) & 1u);
  return (unsigned short)(u >> 16);
}
__device__ __forceinline__ unsigned int pack2(float a, float b){
  return (unsigned int)f2bf(a) | ((unsigned int)f2bf(b) << 16);
}
__device__ __forceinline__ float bflo(unsigned int w){ return __builtin_bit_cast(float, w << 16); }
__device__ __forceinline__ float bfhi(unsigned int w){ return __builtin_bit_cast(float, w & 0xffff0000u); }

// ---------------- CSR build ----------------
__global__ void k_hist(const int* __restrict__ r0, const int* __restrict__ r1, int* __restrict__ cnt){
  int i = blockIdx.x * 256 + threadIdx.x;
  if (i < 2*EE){
    int s = (i >= EE);
    int r = s ? r1[i - EE] : r0[i];
    atomicAdd(&cnt[s*NN + r], 1);
  }
}

__global__ __launch_bounds__(1024) void k_scan(const int* __restrict__ cnt, int* __restrict__ row_ptr, int* __restrict__ rp_work){
  int sup = blockIdx.x;
  const int* c = cnt + sup*NN;
  __shared__ int part[1024];
  int t = threadIdx.x;
  int loc[8]; int s = 0;
  #pragma unroll
  for (int j=0;j<8;j++){ int idx=t*8+j; int v = (idx<NN)? c[idx]:0; loc[j]=s; s+=v; }
  part[t]=s; __syncthreads();
  for (int o=1;o<1024;o<<=1){
    int v = (t>=o)? part[t-o]:0;
    __syncthreads();
    part[t]+=v;
    __syncthreads();
  }
  int pre = (t>0)? part[t-1]:0;
  #pragma unroll
  for (int j=0;j<8;j++){ int idx=t*8+j; if(idx<NN){ int e=pre+loc[j]; row_ptr[sup*(NN+1)+idx]=e; rp_work[sup*NN+idx]=e; } }
  if (t==1023) row_ptr[sup*(NN+1)+NN] = part[1023];
}

__global__ void k_scatter(const int* __restrict__ r0, const int* __restrict__ c0, const float* __restrict__ v0,
                          const int* __restrict__ r1, const int* __restrict__ c1, const float* __restrict__ v1,
                          int* __restrict__ rp_work, int* __restrict__ col_s, float* __restrict__ val_s){
  int i = blockIdx.x * 256 + threadIdx.x;
  if (i < 2*EE){
    int s = (i >= EE);
    int e = s ? i - EE : i;
    int r  = s ? r1[e] : r0[e];
    int cc = s ? c1[e] : c0[e];
    float vv = s ? v1[e] : v0[e];
    int pos = atomicAdd(&rp_work[s*NN + r], 1);
    col_s[s*EE + pos] = cc;
    val_s[s*EE + pos] = vv;
  }
}

// ---------------- weight repack (Chebyshev absorbed), transposed [o][k], bf16 ----------------
// k in [0,320): m=k>>6, u=k&63, f=2+u ; k in [320,330): j=k-320, m=j>>1, d=j&1, f=d ; k>=330: 0
__global__ void k_wpack(const float* __restrict__ W_ru, const float* __restrict__ W_c,
                        unsigned short* __restrict__ Wru_t, unsigned short* __restrict__ Wc_t){
  int i = blockIdx.x * 256 + threadIdx.x;   // 352*192 total
  int k = i / 192; int oo = i % 192;
  const float* W; int ld; unsigned short* dst; int o;
  if (oo < 128){ W = W_ru; ld = 128; dst = Wru_t; o = oo; }
  else         { W = W_c;  ld = 64;  dst = Wc_t;  o = oo - 128; }
  float v = 0.f;
  if (k < 330){
    int m, fb;
    if (k < 320){ m = k >> 6; fb = (2 + (k & 63)) * 5; }
    else        { int j = k - 320; m = j >> 1; fb = (j & 1) * 5; }
    if      (m==0) v = W[(fb+0)*ld+o] - W[(fb+2)*ld+o] - W[(fb+4)*ld+o];
    else if (m==1) v = W[(fb+1)*ld+o];
    else if (m==2) v = 2.f*W[(fb+2)*ld+o];
    else if (m==3) v = W[(fb+3)*ld+o];
    else           v = 2.f*W[(fb+4)*ld+o];
  }
  dst[o*KP + k] = f2bf(v);
}

// ---------------- build x0 (transpose + bf16) ----------------
// xs_state[0][n][b][u] = bf16(hx[b][n*64+u]) ; xs_in[0][n][b][d] = bf16(inputs[b][n*2+d])
__global__ void k_x0(const float* __restrict__ inputs, const float* __restrict__ hx,
                     unsigned int* __restrict__ xs0_dw, unsigned int* __restrict__ xsin0_dw){
  int n = blockIdx.x, t = threadIdx.x;
  int up = t & 31, bq = t >> 5;
  #pragma unroll
  for (int i=0;i<4;i++){
    int b = bq*4 + i;
    const float2 h = *(const float2*)(hx + (size_t)b*HXS + n*64 + up*2);
    xs0_dw[(n*32 + b)*32 + up] = pack2(h.x, h.y);
  }
  if (t < 32){
    int b = t;
    const float2 g = *(const float2*)(inputs + (size_t)b*(NN*2) + n*2);
    xsin0_dw[n*32 + b] = pack2(g.x, g.y);
  }
}

// ---------------- SpMM: dst[n] = sum_{e in row n} val_e * src[col_e] ----------------
// state row = 32b x 64u bf16 = 4096B = 256 lanes * 16B ; in row = 32b x 2d bf16 = 128B (lanes 0..7)
template<bool WITH_IN>
__global__ void k_spmm(const int* __restrict__ row_ptr, const int* __restrict__ col_s, const float* __restrict__ val_s,
                       const uint4* __restrict__ srcS, uint4* __restrict__ dstS,
                       const uint4* __restrict__ srcI, uint4* __restrict__ dstI){
  int n = blockIdx.x, t = threadIdx.x;
  int beg = row_ptr[n], end = row_ptr[n+1];
  float a[8] = {0.f,0.f,0.f,0.f,0.f,0.f,0.f,0.f};
  float ai[8] = {0.f,0.f,0.f,0.f,0.f,0.f,0.f,0.f};
  for (int e = beg; e < end; ++e){
    int c = col_s[e];
    float v = val_s[e];
    uint4 q = srcS[(size_t)c*256 + t];
    a[0]+=v*bflo(q.x); a[1]+=v*bfhi(q.x); a[2]+=v*bflo(q.y); a[3]+=v*bfhi(q.y);
    a[4]+=v*bflo(q.z); a[5]+=v*bfhi(q.z); a[6]+=v*bflo(q.w); a[7]+=v*bfhi(q.w);
    if (WITH_IN && t < 8){
      uint4 qi = srcI[(size_t)c*8 + t];
      ai[0]+=v*bflo(qi.x); ai[1]+=v*bfhi(qi.x); ai[2]+=v*bflo(qi.y); ai[3]+=v*bfhi(qi.y);
      ai[4]+=v*bflo(qi.z); ai[5]+=v*bfhi(qi.z); ai[6]+=v*bflo(qi.w); ai[7]+=v*bfhi(qi.w);
    }
  }
  uint4 o;
  o.x = pack2(a[0],a[1]); o.y = pack2(a[2],a[3]); o.z = pack2(a[4],a[5]); o.w = pack2(a[6],a[7]);
  dstS[(size_t)n*256 + t] = o;
  if (WITH_IN && t < 8){
    uint4 oi;
    oi.x = pack2(ai[0],ai[1]); oi.y = pack2(ai[2],ai[3]); oi.z = pack2(ai[4],ai[5]); oi.w = pack2(ai[6],ai[7]);
    dstI[(size_t)n*8 + t] = oi;
  }
}

// ---------------- fused GEMM (+bias+activation+epilogue), MFMA bf16 ----------------
// A: rows=(n,b) 128/block, K=352 ; B: Wt[o][k] ; out 128 x NCOL
template<int NCOL, bool IS_RU>
__global__ __launch_bounds__(256) void k_gemm(const unsigned short* xsS,           // [5][NB][64] bf16
                                              const unsigned int* __restrict__ xsI, // [5][NB] dword(2 bf16)
                                              const unsigned short* __restrict__ Wt,// [NCOL][KP] bf16
                                              const float* __restrict__ bias,
                                              const float* __restrict__ hx,
                                              float* uout,                          // IS_RU: u_buf ; else: d_out
                                              unsigned short* rhx_dst,              // IS_RU: xs_state[0]
                                              const float* __restrict__ ubr){       // !IS_RU: u_buf
  constexpr int CF = NCOL / 16;
  __shared__ unsigned short Al[128*64];
  __shared__ unsigned short Bl[NCOL*64];
  const int t = threadIdx.x;
  const int wv = t >> 6;
  const int l = t & 63;
  const int R0 = blockIdx.x * 128;

  f32x4 acc[2][CF];
  const f32x4 zero = {0.f, 0.f, 0.f, 0.f};
  #pragma unroll
  for (int rf=0; rf<2; rf++)
    #pragma unroll
    for (int cf=0; cf<CF; cf++) acc[rf][cf] = zero;

  for (int m=0; m<5; m++){
    // stage A tile [128 rows][64 k] with XOR swizzle (16B units: c ^= r&7)
    #pragma unroll
    for (int i=0;i<4;i++){
      int s = t + i*256; int r = s >> 3; int c = s & 7;
      uint4 q = ((const uint4*)(xsS + ((size_t)m*NB + R0 + r)*64))[c];
      *(uint4*)(&Al[r*64 + ((c ^ (r&7)) << 3)]) = q;
    }
    // stage B tile [NCOL rows][64 k]
    #pragma unroll
    for (int i=0;i<NCOL*8/256;i++){
      int s = t + i*256; int r = s >> 3; int c = s & 7;
      uint4 q = ((const uint4*)(Wt + r*KP + m*64))[c];
      *(uint4*)(&Bl[r*64 + ((c ^ (r&7)) << 3)]) = q;
    }
    __syncthreads();
    #pragma unroll
    for (int ks=0; ks<2; ks++){
      bf16x8 af[2];
      #pragma unroll
      for (int rf=0; rf<2; rf++){
        int row = wv*32 + rf*16 + (l & 15);
        int unit = (ks*4 + (l >> 4)) ^ (row & 7);
        af[rf] = __builtin_bit_cast(bf16x8, *(const uint4*)(&Al[row*64 + unit*8]));
      }
      #pragma unroll
      for (int cf=0; cf<CF; cf++){
        int col = cf*16 + (l & 15);
        int unit = (ks*4 + (l >> 4)) ^ (col & 7);
        bf16x8 bv = __builtin_bit_cast(bf16x8, *(const uint4*)(&Bl[col*64 + unit*8]));
        acc[0][cf] = __builtin_amdgcn_mfma_f32_16x16x32_bf16(af[0], bv, acc[0][cf], 0, 0, 0);
        acc[1][cf] = __builtin_amdgcn_mfma_f32_16x16x32_bf16(af[1], bv, acc[1][cf], 0, 0, 0);
      }
    }
    __syncthreads();
  }
  // remainder K-step: input features, k local = m*2+d (10 real, pad to 32). 64B rows, swizzle c ^= r&3.
  #pragma unroll
  for (int i=0;i<8;i++){
    int s = t + i*256;              // 128 rows * 16 dwords
    int r = s >> 4; int dw = s & 15;
    unsigned int v = (dw < 5) ? xsI[(size_t)dw*NB + R0 + r] : 0u;
    *(unsigned int*)(&Al[r*32 + (((dw>>2) ^ (r&3)) << 3) + ((dw&3) << 1)]) = v;
  }
  #pragma unroll
  for (int i=0;i<NCOL*4/256;i++){
    int s = t + i*256; int r = s >> 2; int c = s & 3;
    uint4 q = ((const uint4*)(Wt + r*KP + 320))[c];
    *(uint4*)(&Bl[r*32 + ((c ^ (r&3)) << 3)]) = q;
  }
  __syncthreads();
  {
    bf16x8 af[2];
    #pragma unroll
    for (int rf=0; rf<2; rf++){
      int row = wv*32 + rf*16 + (l & 15);
      int unit = (l >> 4) ^ (row & 3);
      af[rf] = __builtin_bit_cast(bf16x8, *(const uint4*)(&Al[row*32 + unit*8]));
    }
    #pragma unroll
    for (int cf=0; cf<CF; cf++){
      int col = cf*16 + (l & 15);
      int unit = (l >> 4) ^ (col & 3);
      bf16x8 bv = __builtin_bit_cast(bf16x8, *(const uint4*)(&Bl[col*32 + unit*8]));
      acc[0][cf] = __builtin_amdgcn_mfma_f32_16x16x32_bf16(af[0], bv, acc[0][cf], 0, 0, 0);
      acc[1][cf] = __builtin_amdgcn_mfma_f32_16x16x32_bf16(af[1], bv, acc[1][cf], 0, 0, 0);
    }
  }
  // epilogue: C/D layout col=lane&15, row=(lane>>4)*4+reg
  #pragma unroll
  for (int rf=0; rf<2; rf++){
    #pragma unroll
    for (int reg=0; reg<4; reg++){
      int row = R0 + wv*32 + rf*16 + ((l >> 4) << 2) + reg;
      int n = row >> 5, b = row & 31;
      size_t rowoff = (size_t)b*HXS + (size_t)n*UU;
      #pragma unroll
      for (int cf=0; cf<CF; cf++){
        int col = cf*16 + (l & 15);
        float v = acc[rf][cf][reg] + bias[col];
        if constexpr (IS_RU){
          float sg = 1.f / (1.f + __expf(-v));
          if (cf < 4){ // col < 64 -> r : write r*hx as bf16 into xs_state[0] (in place)
            float h = hx[rowoff + col];
            rhx_dst[(size_t)row*64 + col] = f2bf(sg * h);
          } else {     // col >= 64 -> u
            uout[rowoff + (col - 64)] = sg;
          }
        } else {
          float cc = tanhf(v);
          float uu = ubr[rowoff + col];
          float h  = hx[rowoff + col];
          uout[rowoff + col] = uu*h + (1.f - uu)*cc;
        }
      }
    }
  }
}

// ---------------- launcher ----------------
extern "C" void kernel_launch(void* const* d_in, const int* in_sizes, int n_in,
                              void* d_out, int out_size, void* d_ws, size_t ws_size,
                              hipStream_t stream){
  const float* inputs = (const float*)d_in[0];
  const float* hx     = (const float*)d_in[1];
  const int*   row0   = (const int*)d_in[2];
  const int*   col0   = (const int*)d_in[3];
  const float* val0   = (const float*)d_in[4];
  const int*   row1   = (const int*)d_in[5];
  const int*   col1   = (const int*)d_in[6];
  const float* val1   = (const float*)d_in[7];
  const float* W_ru   = (const float*)d_in[8];
  const float* b_ru   = (const float*)d_in[9];
  const float* W_c    = (const float*)d_in[10];
  const float* b_c    = (const float*)d_in[11];
  float* out = (float*)d_out;

  char* ws = (char*)d_ws;
  size_t off = 0;
  auto alloc = [&](size_t bytes) -> void* {
    void* p = ws + off;
    off += (bytes + 255) & ~(size_t)255;
    return p;
  };
  unsigned short* xsS   = (unsigned short*)alloc((size_t)5*NB*64*2); // 163.84 MB
  unsigned int*   xsI   = (unsigned int*)  alloc((size_t)5*NB*4);    //   5.12 MB
  float*          u_buf = (float*)         alloc((size_t)NB*64*4);   //  65.54 MB
  unsigned short* Wru_t = (unsigned short*)alloc(128*KP*2);
  unsigned short* Wc_t  = (unsigned short*)alloc(64*KP*2);
  int*   row_ptr = (int*)  alloc(2*(NN+1)*4);
  int*   col_s   = (int*)  alloc(2*EE*4);
  float* val_s   = (float*)alloc(2*EE*4);
  int*   cnt     = (int*)  alloc(2*NN*4);
  int*   rp_work = (int*)  alloc(2*NN*4);
  (void)ws_size; (void)in_sizes; (void)n_in; (void)out_size;

  hipMemsetAsync(cnt, 0, 2*NN*4, stream);
  k_hist<<<(2*EE + 255)/256, 256, 0, stream>>>(row0, row1, cnt);
  k_scan<<<2, 1024, 0, stream>>>(cnt, row_ptr, rp_work);
  k_scatter<<<(2*EE + 255)/256, 256, 0, stream>>>(row0, col0, val0, row1, col1, val1, rp_work, col_s, val_s);
  k_wpack<<<(KP*192)/256, 256, 0, stream>>>(W_ru, W_c, Wru_t, Wc_t);
  k_x0<<<NN, 256, 0, stream>>>(inputs, hx, (unsigned int*)xsS, xsI);

  auto spmm = [&](int sup, int srcm, int dstm, bool win){
    const int* rp = row_ptr + sup*(NN+1);
    const int* cs = col_s + sup*EE;
    const float* vs = val_s + sup*EE;
    const uint4* sS = (const uint4*)(xsS + (size_t)srcm*NB*64);
    uint4* dS = (uint4*)(xsS + (size_t)dstm*NB*64);
    const uint4* sI = (const uint4*)(xsI + (size_t)srcm*NB);
    uint4* dI = (uint4*)(xsI + (size_t)dstm*NB);
    if (win) k_spmm<true ><<<NN, 256, 0, stream>>>(rp, cs, vs, sS, dS, sI, dI);
    else     k_spmm<false><<<NN, 256, 0, stream>>>(rp, cs, vs, sS, dS, nullptr, nullptr);
  };

  // gconv 1 (r,u gates): diffuse state+input features
  spmm(0, 0, 1, true);
  spmm(0, 1, 2, true);
  spmm(1, 0, 3, true);
  spmm(1, 3, 4, true);
  k_gemm<128, true><<<NB/128, 256, 0, stream>>>(xsS, xsI, Wru_t, b_ru, hx, u_buf, xsS, nullptr);

  // gconv 2 (candidate): input-part diffusion reused from gconv1; state part is r*hx (written in-place to xs_state[0])
  spmm(0, 0, 1, false);
  spmm(0, 1, 2, false);
  spmm(1, 0, 3, false);
  spmm(1, 3, 4, false);
  k_gemm<64, false><<<NB/128, 256, 0, stream>>>(xsS, xsI, Wc_t, b_c, hx, out, nullptr, u_buf);
}